// Round 11
// baseline (233.278 us; speedup 1.0000x reference)
//
#include <hip/hip_runtime.h>
#include <hip/hip_bf16.h>
#include <math.h>

#define N_EMBD 1024
#define N_HEAD 16
#define HEAD_DIM 64
#define BSZ 2
#define TSEQ 2048
#define C3 (3 * N_EMBD)

typedef __attribute__((ext_vector_type(8))) short short8_t;
typedef __attribute__((ext_vector_type(4))) float f32x4;
typedef __attribute__((address_space(3))) unsigned int lds_u32;
typedef const __attribute__((address_space(1))) unsigned int glb_u32;

__device__ __forceinline__ unsigned short f2bf(float f) {
  return __builtin_bit_cast(unsigned short, __float2bfloat16(f));
}

// ---------------- fp32 -> bf16 vectorized convert (8 elems/thread/iter) --------
__global__ __launch_bounds__(256) void conv_vec(
    const float* __restrict__ in, unsigned short* __restrict__ out, int n8)
{
  for (int i = blockIdx.x * blockDim.x + threadIdx.x; i < n8;
       i += gridDim.x * blockDim.x) {
    float4 a = ((const float4*)in)[2 * i];
    float4 b = ((const float4*)in)[2 * i + 1];
    union { unsigned short u[8]; uint4 q; } t;
    t.u[0] = f2bf(a.x); t.u[1] = f2bf(a.y); t.u[2] = f2bf(a.z); t.u[3] = f2bf(a.w);
    t.u[4] = f2bf(b.x); t.u[5] = f2bf(b.y); t.u[6] = f2bf(b.z); t.u[7] = f2bf(b.w);
    ((uint4*)out)[i] = t.q;
  }
}

// ------------- fp32 [K,N] -> bf16 [N,K] transpose-convert, 32x32 LDS tiles -----
__global__ __launch_bounds__(256) void conv_transpose(
    const float* __restrict__ in, unsigned short* __restrict__ out, int K, int N)
{
  __shared__ float tile[32][33];
  const int bk = blockIdx.y * 32, bn = blockIdx.x * 32;
  const int r = threadIdx.x >> 3, c4 = (threadIdx.x & 7) * 4;
  *(float4*)&tile[r][c4] = *(const float4*)(in + (size_t)(bk + r) * N + bn + c4);
  __syncthreads();
  union { unsigned short u[4]; uint2 q; } t;
#pragma unroll
  for (int j = 0; j < 4; ++j) t.u[j] = f2bf(tile[c4 + j][r]);
  *(uint2*)(out + (size_t)(bn + r) * K + bk + c4) = t.q;
}

// ------------- V slice of qkv [B,T,3C] -> VT [B*H, D, T] bf16 transpose -------
// One-time transpose so attention can stage V^T rows with wide coalesced loads
// instead of a 16-scalar-load gather per thread per chunk (done ~16.5x/chunk).
__global__ __launch_bounds__(256) void conv_vT(
    const unsigned short* __restrict__ qkv, unsigned short* __restrict__ vt)
{
  __shared__ unsigned short tile[32][36];   // 36 u16 row stride -> 8B-aligned rows
  const int t0 = blockIdx.x * 32;
  const int d0 = blockIdx.y * 32;
  const int bh = blockIdx.z;                // b*N_HEAD + h
  const int b = bh >> 4, h = bh & 15;
  const int r = threadIdx.x >> 3, c4 = (threadIdx.x & 7) * 4;
  const unsigned short* src =
      qkv + ((size_t)b * TSEQ + t0 + r) * C3 + 2 * N_EMBD + h * HEAD_DIM + d0 + c4;
  *(uint2*)&tile[r][c4] = *(const uint2*)src;
  __syncthreads();
  union { unsigned short u[4]; uint2 q; } o;
#pragma unroll
  for (int j = 0; j < 4; ++j) o.u[j] = tile[c4 + j][r];
  *(uint2*)(vt + ((size_t)bh * HEAD_DIM + d0 + r) * TSEQ + t0 + c4) = o.q;
}

// ---------------- bf16 MFMA GEMM: C[M,N] = A[M,K] @ Bt[N,K]^T + bias ----------
// 128x128 tile, BK=32, 256 thr = 4 waves (2x2), each wave 64x64 (4x4 frags).
template <typename OUT_T>
__global__ __launch_bounds__(256) void gemm_mfma(
    const unsigned short* __restrict__ A,   // [M,K] bf16
    const unsigned short* __restrict__ Bt,  // [N,K] bf16
    const float* __restrict__ bias,         // [N]
    OUT_T* __restrict__ C, int M, int N, int K)
{
  constexpr int BM = 128, BN = 128, BK = 32;
  __shared__ __align__(16) unsigned short As[BM * BK];
  __shared__ __align__(16) unsigned short Bs[BN * BK];

  const int tid = threadIdx.x;
  const int l = tid & 63;
  const int g = l >> 4, c = l & 15;
  const int w = tid >> 6;
  const int wr = w >> 1, wc = w & 1;
  const int bm = blockIdx.y * BM, bn = blockIdx.x * BN;

  f32x4 acc[4][4];
#pragma unroll
  for (int i = 0; i < 4; i++)
#pragma unroll
    for (int j = 0; j < 4; j++) acc[i][j] = (f32x4){0.f, 0.f, 0.f, 0.f};

  int srow[2], skq[2];
#pragma unroll
  for (int i = 0; i < 2; i++) {
    int seg = i * 256 + tid;
    srow[i] = seg >> 2;
    skq[i] = (seg & 3) ^ (srow[i] & 3);
  }

  for (int k0 = 0; k0 < K; k0 += BK) {
    __syncthreads();
#pragma unroll
    for (int i = 0; i < 2; i++) {
      int seg = i * 256 + tid;
      __builtin_amdgcn_global_load_lds(
          (glb_u32*)(A + (size_t)(bm + srow[i]) * K + k0 + skq[i] * 8),
          (lds_u32*)((char*)As + seg * 16), 16, 0, 0);
      __builtin_amdgcn_global_load_lds(
          (glb_u32*)(Bt + (size_t)(bn + srow[i]) * K + k0 + skq[i] * 8),
          (lds_u32*)((char*)Bs + seg * 16), 16, 0, 0);
    }
    __syncthreads();

    short8_t af[4], bf[4];
#pragma unroll
    for (int mi = 0; mi < 4; mi++) {
      int row = wr * 64 + mi * 16 + c;
      af[mi] = *(const short8_t*)((char*)As + row * 64 + ((g * 16) ^ ((row & 3) << 4)));
    }
#pragma unroll
    for (int ni = 0; ni < 4; ni++) {
      int row = wc * 64 + ni * 16 + c;
      bf[ni] = *(const short8_t*)((char*)Bs + row * 64 + ((g * 16) ^ ((row & 3) << 4)));
    }
    __builtin_amdgcn_s_setprio(1);
#pragma unroll
    for (int mi = 0; mi < 4; mi++)
#pragma unroll
      for (int ni = 0; ni < 4; ni++)
        acc[mi][ni] = __builtin_amdgcn_mfma_f32_16x16x32_bf16(af[mi], bf[ni], acc[mi][ni], 0, 0, 0);
    __builtin_amdgcn_s_setprio(0);
  }

  float bv[4];
#pragma unroll
  for (int ni = 0; ni < 4; ni++) bv[ni] = bias[bn + wc * 64 + ni * 16 + c];
#pragma unroll
  for (int mi = 0; mi < 4; mi++)
#pragma unroll
    for (int j = 0; j < 4; j++) {
      int row = bm + wr * 64 + mi * 16 + g * 4 + j;
      OUT_T* cp = C + (size_t)row * N + bn + wc * 64 + c;
#pragma unroll
      for (int ni = 0; ni < 4; ni++) {
        float v = acc[mi][ni][j] + bv[ni];
        if constexpr (sizeof(OUT_T) == 2)
          *(unsigned short*)(cp + ni * 16) = f2bf(v);
        else
          *(float*)(cp + ni * 16) = v;
      }
    }
}

// ---------------- MFMA bf16 flash attention (bf16 qkv + VT in, bf16 y out) -----
// Round-10 changes vs verified 97us body (schedule/pairing/PV identical):
// (1) V staged from pre-transposed VT global with 2x uint4 K-style loads
//     (replaces 16 scalar strided loads + addr chains per thread per chunk),
// (2) log2-domain softmax: st*(0.125*log2e) then exp2f (drops the mul inside
//     every __expf), unconditional rescale kept,
// (3) mask-select dropped from the p-pass (masked st=-1e30 -> exp2 -> 0 exactly;
//     every row's first chunk k0=0 has valid keys so m[r] is always finite here),
// (4) wave-uniform `full` fast-path skips mask-select in the s-pass (29/33 chunks).
__global__ __launch_bounds__(256) void attn_mfma(
    const unsigned short* __restrict__ qkv,
    const unsigned short* __restrict__ vt,   // [B*H, D, T]
    unsigned short* __restrict__ y)
{
  const int l = threadIdx.x & 63;
  const int w = threadIdx.x >> 6;
  const int b = blockIdx.z, h = blockIdx.y;
  const int pair = blockIdx.x;          // 0..15
  const int g = l >> 4;
  const int c = l & 15;

  __shared__ __align__(16) unsigned short Ks[64 * 64];
  __shared__ __align__(16) unsigned short Vt[64 * 64];
  __shared__ __align__(16) unsigned short Ps[4][16 * 64];

  const unsigned short* base = qkv + (size_t)b * TSEQ * C3;
  const unsigned short* vbase = vt + (size_t)(b * N_HEAD + h) * HEAD_DIM * TSEQ;
  const float SCALE_LOG2E = 0.125f * 1.44269504f;

#pragma unroll 1
  for (int half = 0; half < 2; ++half) {
    const int tile = half == 0 ? (31 - pair) : pair;   // heavy tile first
    const int r0 = tile * 64;
    const int qr0 = r0 + w * 16;

    short8_t qf[2];
    {
      const unsigned short* qp = base + (size_t)(qr0 + c) * C3 + h * HEAD_DIM + g * 8;
      qf[0] = *(const short8_t*)(qp);
      qf[1] = *(const short8_t*)(qp + 32);
    }

    f32x4 o[4];
    float m[4], ld[4];
#pragma unroll
    for (int dt = 0; dt < 4; ++dt) o[dt] = (f32x4){0.f, 0.f, 0.f, 0.f};
#pragma unroll
    for (int r = 0; r < 4; ++r) { m[r] = -1e30f; ld[r] = 0.f; }

    const int nch = tile + 1;
#pragma unroll 1
    for (int ci = 0; ci < nch; ++ci) {
      const int k0 = ci * 64;
      __syncthreads();
      // ---- stage K: 64x64 bf16 row-major, XOR-swizzled ----
#pragma unroll
      for (int s = 0; s < 2; ++s) {
        int seg = threadIdx.x + s * 256;
        int kr = seg >> 3, d8 = (seg & 7) * 8;
        uint4 t = *(const uint4*)(base + (size_t)(k0 + kr) * C3 + N_EMBD + h * HEAD_DIM + d8);
        *(uint4*)((char*)Ks + kr * 128 + ((d8 * 2) ^ ((kr & 7) << 4))) = t;
      }
      // ---- stage V^T rows from VT global: Vt[d][k], XOR-swizzled ----
#pragma unroll
      for (int s = 0; s < 2; ++s) {
        int seg = threadIdx.x + s * 256;
        int dr = seg >> 3, k8 = (seg & 7) * 8;
        uint4 t = *(const uint4*)(vbase + (size_t)dr * TSEQ + k0 + k8);
        *(uint4*)((char*)Vt + dr * 128 + ((k8 * 2) ^ ((dr & 7) << 4))) = t;
      }
      __syncthreads();
      if (k0 > qr0 + 15) continue;

      // ---- S = Q K^T ----
      f32x4 st[4];
      __builtin_amdgcn_s_setprio(1);
#pragma unroll
      for (int kt = 0; kt < 4; ++kt) {
        const int row = kt * 16 + c;
        short8_t kf0 = *(const short8_t*)((const char*)Ks + row * 128 + ((g * 16) ^ ((row & 7) << 4)));
        short8_t kf1 = *(const short8_t*)((const char*)Ks + row * 128 + ((64 + g * 16) ^ ((row & 7) << 4)));
        f32x4 a2 = (f32x4){0.f, 0.f, 0.f, 0.f};
        a2 = __builtin_amdgcn_mfma_f32_16x16x32_bf16(qf[0], kf0, a2, 0, 0, 0);
        a2 = __builtin_amdgcn_mfma_f32_16x16x32_bf16(qf[1], kf1, a2, 0, 0, 0);
        st[kt] = a2;
      }
      __builtin_amdgcn_s_setprio(0);

      // ---- online softmax, log2 domain (col=c key, row=g*4+r query) ----
      const bool full = (k0 + 63 <= qr0);   // wave-uniform
#pragma unroll
      for (int r = 0; r < 4; ++r) {
        const int qg = qr0 + g * 4 + r;
        float mx = -1e30f;
#pragma unroll
        for (int kt = 0; kt < 4; ++kt) {
          float s = st[kt][r] * SCALE_LOG2E;
          if (!full) { int kg = k0 + kt * 16 + c; if (kg > qg) s = -1e30f; }
          st[kt][r] = s;
          mx = fmaxf(mx, s);
        }
        mx = fmaxf(mx, __shfl_xor(mx, 1));
        mx = fmaxf(mx, __shfl_xor(mx, 2));
        mx = fmaxf(mx, __shfl_xor(mx, 4));
        mx = fmaxf(mx, __shfl_xor(mx, 8));
        float mnew = fmaxf(m[r], mx);
        float corr = exp2f(m[r] - mnew);
        m[r] = mnew;
        float rs = 0.f;
        const int row = g * 4 + r;
#pragma unroll
        for (int kt = 0; kt < 4; ++kt) {
          float p = exp2f(st[kt][r] - mnew);   // masked st=-1e30 -> 0
          rs += p;
          *(unsigned short*)((char*)Ps[w] + row * 128 +
                             (((kt * 16 + c) * 2) ^ ((row & 7) << 4))) = f2bf(p);
        }
        rs += __shfl_xor(rs, 1);
        rs += __shfl_xor(rs, 2);
        rs += __shfl_xor(rs, 4);
        rs += __shfl_xor(rs, 8);
        ld[r] = ld[r] * corr + rs;
#pragma unroll
        for (int dt = 0; dt < 4; ++dt) o[dt][r] *= corr;
      }
      // ---- O += P V ----
      short8_t pf[2];
#pragma unroll
      for (int kc = 0; kc < 2; ++kc)
        pf[kc] = *(const short8_t*)((const char*)Ps[w] + c * 128 +
                                    ((64 * kc + g * 16) ^ ((c & 7) << 4)));
      __builtin_amdgcn_s_setprio(1);
#pragma unroll
      for (int dt = 0; dt < 4; ++dt) {
        const int row = dt * 16 + c;
#pragma unroll
        for (int kc = 0; kc < 2; ++kc) {
          short8_t vf = *(const short8_t*)((const char*)Vt + row * 128 +
                                           ((64 * kc + g * 16) ^ ((row & 7) << 4)));
          o[dt] = __builtin_amdgcn_mfma_f32_16x16x32_bf16(pf[kc], vf, o[dt], 0, 0, 0);
        }
      }
      __builtin_amdgcn_s_setprio(0);
    }
    // ---- epilogue: write bf16 ----
#pragma unroll
    for (int r = 0; r < 4; ++r) {
      float inv = 1.f / ld[r];
      const size_t rowoff = ((size_t)b * TSEQ + qr0 + g * 4 + r) * N_EMBD + h * HEAD_DIM;
#pragma unroll
      for (int dt = 0; dt < 4; ++dt)
        y[rowoff + dt * 16 + c] = f2bf(o[dt][r] * inv);
    }
  }
}

extern "C" void kernel_launch(void* const* d_in, const int* in_sizes, int n_in,
                              void* d_out, int out_size, void* d_ws, size_t ws_size,
                              hipStream_t stream) {
  const float* x      = (const float*)d_in[0];
  const float* W_attn = (const float*)d_in[1];
  const float* b_attn = (const float*)d_in[2];
  const float* W_proj = (const float*)d_in[3];
  const float* b_proj = (const float*)d_in[4];
  float* out = (float*)d_out;

  const int M = BSZ * TSEQ;  // 4096

  unsigned short* xb   = (unsigned short*)d_ws;                 // [M,C]      8.4 MB
  unsigned short* Wta  = xb + (size_t)M * N_EMBD;               // [3C,C]     6.3 MB
  unsigned short* Wtp  = Wta + (size_t)C3 * N_EMBD;             // [C,C]      2.1 MB
  unsigned short* qkvb = Wtp + (size_t)N_EMBD * N_EMBD;         // [B,T,3C]  25.2 MB
  unsigned short* yatt = qkvb + (size_t)M * C3;                 // [B,T,C]    8.4 MB
  unsigned short* vtb  = yatt + (size_t)M * N_EMBD;             // [B*H,D,T]  8.4 MB

  conv_vec<<<2048, 256, 0, stream>>>(x, xb, M * N_EMBD / 8);
  conv_transpose<<<dim3(C3 / 32, N_EMBD / 32), 256, 0, stream>>>(W_attn, Wta, N_EMBD, C3);
  conv_transpose<<<dim3(N_EMBD / 32, N_EMBD / 32), 256, 0, stream>>>(W_proj, Wtp, N_EMBD, N_EMBD);

  gemm_mfma<unsigned short><<<dim3(C3 / 128, M / 128), 256, 0, stream>>>(
      xb, Wta, b_attn, qkvb, M, C3, N_EMBD);

  conv_vT<<<dim3(TSEQ / 32, HEAD_DIM / 32, BSZ * N_HEAD), 256, 0, stream>>>(qkvb, vtb);

  // paired q-tiles: grid.x = (T/64)/2 = 16, each block does 2 tiles (33 chunks)
  attn_mfma<<<dim3(TSEQ / 128, N_HEAD, BSZ), 256, 0, stream>>>(qkvb, vtb, yatt);

  gemm_mfma<float><<<dim3(N_EMBD / 128, M / 128), 256, 0, stream>>>(
      yatt, Wtp, b_proj, out, M, N_EMBD, N_EMBD);
}

// Round 12
// 218.267 us; speedup vs baseline: 1.0688x; 1.0688x over previous
//
#include <hip/hip_runtime.h>
#include <hip/hip_bf16.h>
#include <math.h>

#define N_EMBD 1024
#define N_HEAD 16
#define HEAD_DIM 64
#define BSZ 2
#define TSEQ 2048
#define C3 (3 * N_EMBD)

typedef __attribute__((ext_vector_type(8))) short short8_t;
typedef __attribute__((ext_vector_type(4))) float f32x4;
typedef __attribute__((address_space(3))) unsigned int lds_u32;
typedef const __attribute__((address_space(1))) unsigned int glb_u32;

__device__ __forceinline__ unsigned short f2bf(float f) {
  return __builtin_bit_cast(unsigned short, __float2bfloat16(f));
}

// ---------------- fp32 -> bf16 vectorized convert (8 elems/thread/iter) --------
__global__ __launch_bounds__(256) void conv_vec(
    const float* __restrict__ in, unsigned short* __restrict__ out, int n8)
{
  for (int i = blockIdx.x * blockDim.x + threadIdx.x; i < n8;
       i += gridDim.x * blockDim.x) {
    float4 a = ((const float4*)in)[2 * i];
    float4 b = ((const float4*)in)[2 * i + 1];
    union { unsigned short u[8]; uint4 q; } t;
    t.u[0] = f2bf(a.x); t.u[1] = f2bf(a.y); t.u[2] = f2bf(a.z); t.u[3] = f2bf(a.w);
    t.u[4] = f2bf(b.x); t.u[5] = f2bf(b.y); t.u[6] = f2bf(b.z); t.u[7] = f2bf(b.w);
    ((uint4*)out)[i] = t.q;
  }
}

// ------------- fp32 [K,N] -> bf16 [N,K] transpose-convert, 32x32 LDS tiles -----
__global__ __launch_bounds__(256) void conv_transpose(
    const float* __restrict__ in, unsigned short* __restrict__ out, int K, int N)
{
  __shared__ float tile[32][33];
  const int bk = blockIdx.y * 32, bn = blockIdx.x * 32;
  const int r = threadIdx.x >> 3, c4 = (threadIdx.x & 7) * 4;
  *(float4*)&tile[r][c4] = *(const float4*)(in + (size_t)(bk + r) * N + bn + c4);
  __syncthreads();
  union { unsigned short u[4]; uint2 q; } t;
#pragma unroll
  for (int j = 0; j < 4; ++j) t.u[j] = f2bf(tile[c4 + j][r]);
  *(uint2*)(out + (size_t)(bn + r) * K + bk + c4) = t.q;
}

// ------------- V slice of qkv [B,T,3C] -> VT [B*H, D, T] bf16 transpose -------
__global__ __launch_bounds__(256) void conv_vT(
    const unsigned short* __restrict__ qkv, unsigned short* __restrict__ vt)
{
  __shared__ unsigned short tile[32][36];
  const int t0 = blockIdx.x * 32;
  const int d0 = blockIdx.y * 32;
  const int bh = blockIdx.z;
  const int b = bh >> 4, h = bh & 15;
  const int r = threadIdx.x >> 3, c4 = (threadIdx.x & 7) * 4;
  const unsigned short* src =
      qkv + ((size_t)b * TSEQ + t0 + r) * C3 + 2 * N_EMBD + h * HEAD_DIM + d0 + c4;
  *(uint2*)&tile[r][c4] = *(const uint2*)src;
  __syncthreads();
  union { unsigned short u[4]; uint2 q; } o;
#pragma unroll
  for (int j = 0; j < 4; ++j) o.u[j] = tile[c4 + j][r];
  *(uint2*)(vt + ((size_t)bh * HEAD_DIM + d0 + r) * TSEQ + t0 + c4) = o.q;
}

// ---------------- bf16 MFMA GEMM: C[M,N] = A[M,K] @ Bt[N,K]^T + bias ----------
template <typename OUT_T>
__global__ __launch_bounds__(256) void gemm_mfma(
    const unsigned short* __restrict__ A,
    const unsigned short* __restrict__ Bt,
    const float* __restrict__ bias,
    OUT_T* __restrict__ C, int M, int N, int K)
{
  constexpr int BM = 128, BN = 128, BK = 32;
  __shared__ __align__(16) unsigned short As[BM * BK];
  __shared__ __align__(16) unsigned short Bs[BN * BK];

  const int tid = threadIdx.x;
  const int l = tid & 63;
  const int g = l >> 4, c = l & 15;
  const int w = tid >> 6;
  const int wr = w >> 1, wc = w & 1;
  const int bm = blockIdx.y * BM, bn = blockIdx.x * BN;

  f32x4 acc[4][4];
#pragma unroll
  for (int i = 0; i < 4; i++)
#pragma unroll
    for (int j = 0; j < 4; j++) acc[i][j] = (f32x4){0.f, 0.f, 0.f, 0.f};

  int srow[2], skq[2];
#pragma unroll
  for (int i = 0; i < 2; i++) {
    int seg = i * 256 + tid;
    srow[i] = seg >> 2;
    skq[i] = (seg & 3) ^ (srow[i] & 3);
  }

  for (int k0 = 0; k0 < K; k0 += BK) {
    __syncthreads();
#pragma unroll
    for (int i = 0; i < 2; i++) {
      int seg = i * 256 + tid;
      __builtin_amdgcn_global_load_lds(
          (glb_u32*)(A + (size_t)(bm + srow[i]) * K + k0 + skq[i] * 8),
          (lds_u32*)((char*)As + seg * 16), 16, 0, 0);
      __builtin_amdgcn_global_load_lds(
          (glb_u32*)(Bt + (size_t)(bn + srow[i]) * K + k0 + skq[i] * 8),
          (lds_u32*)((char*)Bs + seg * 16), 16, 0, 0);
    }
    __syncthreads();

    short8_t af[4], bf[4];
#pragma unroll
    for (int mi = 0; mi < 4; mi++) {
      int row = wr * 64 + mi * 16 + c;
      af[mi] = *(const short8_t*)((char*)As + row * 64 + ((g * 16) ^ ((row & 3) << 4)));
    }
#pragma unroll
    for (int ni = 0; ni < 4; ni++) {
      int row = wc * 64 + ni * 16 + c;
      bf[ni] = *(const short8_t*)((char*)Bs + row * 64 + ((g * 16) ^ ((row & 3) << 4)));
    }
    __builtin_amdgcn_s_setprio(1);
#pragma unroll
    for (int mi = 0; mi < 4; mi++)
#pragma unroll
      for (int ni = 0; ni < 4; ni++)
        acc[mi][ni] = __builtin_amdgcn_mfma_f32_16x16x32_bf16(af[mi], bf[ni], acc[mi][ni], 0, 0, 0);
    __builtin_amdgcn_s_setprio(0);
  }

  float bv[4];
#pragma unroll
  for (int ni = 0; ni < 4; ni++) bv[ni] = bias[bn + wc * 64 + ni * 16 + c];
#pragma unroll
  for (int mi = 0; mi < 4; mi++)
#pragma unroll
    for (int j = 0; j < 4; j++) {
      int row = bm + wr * 64 + mi * 16 + g * 4 + j;
      OUT_T* cp = C + (size_t)row * N + bn + wc * 64 + c;
#pragma unroll
      for (int ni = 0; ni < 4; ni++) {
        float v = acc[mi][ni][j] + bv[ni];
        if constexpr (sizeof(OUT_T) == 2)
          *(unsigned short*)(cp + ni * 16) = f2bf(v);
        else
          *(float*)(cp + ni * 16) = v;
      }
    }
}

// ---------------- MFMA bf16 flash attention, in-block chunk-split --------------
// Round-12: 512-thread blocks = 8 waves in 2 chunk-groups. Both groups own the
// same 64 q-rows of the tile; group 0 does even K-chunks, group 1 odd K-chunks,
// each with private K/V LDS buffers and private online (m,l,o). At tile end,
// group 1 writes partials to LDS (overlay on its K/V buffers) and group 0 does
// the exact flash combine and writes y. Doubles waves/CU 8 -> 16 at equal HBM
// traffic. Inner chunk body identical to the verified round-11 kernel.
// LDS layout (u16 idx): K0=0, V0=4096, K1=8192, V1=12288, Ps[w]=16384+w*1024.
// Merge scratch: osc = (float*)(S+8192) overlays K1+V1 (4 waves x 1024 f32);
// m/l scratch in group-1's Ps area.
__global__ __launch_bounds__(512) void attn_mfma(
    const unsigned short* __restrict__ qkv,
    const unsigned short* __restrict__ vt,   // [B*H, D, T]
    unsigned short* __restrict__ y)
{
  const int tid = threadIdx.x;
  const int l = tid & 63;
  const int w = tid >> 6;        // 0..7
  const int g2 = w >> 2;         // chunk group
  const int wg = w & 3;          // q-row slice within tile
  const int tid2 = tid & 255;    // thread index within group
  const int b = blockIdx.z, h = blockIdx.y;
  const int pair = blockIdx.x;   // 0..15
  const int g = l >> 4;
  const int c = l & 15;

  __shared__ __align__(16) unsigned short S[24576];   // 48 KB
  unsigned short* Ksg = S + g2 * 8192;
  unsigned short* Vsg = S + 4096 + g2 * 8192;
  unsigned short* Psw = S + 16384 + w * 1024;
  float* osc = (float*)(S + 8192);                    // 4096 f32 (16 KB)
  float* mlsc = (float*)(S + 16384 + 4 * 1024);       // group-1 Ps area

  const unsigned short* base = qkv + (size_t)b * TSEQ * C3;
  const unsigned short* vbase = vt + (size_t)(b * N_HEAD + h) * HEAD_DIM * TSEQ;
  const float SCALE_LOG2E = 0.125f * 1.44269504f;

#pragma unroll 1
  for (int half = 0; half < 2; ++half) {
    const int tile = half == 0 ? (31 - pair) : pair;   // heavy tile first
    const int qr0 = tile * 64 + wg * 16;

    short8_t qf[2];
    {
      const unsigned short* qp = base + (size_t)(qr0 + c) * C3 + h * HEAD_DIM + g * 8;
      qf[0] = *(const short8_t*)(qp);
      qf[1] = *(const short8_t*)(qp + 32);
    }

    f32x4 o[4];
    float m[4], ld[4];
#pragma unroll
    for (int dt = 0; dt < 4; ++dt) o[dt] = (f32x4){0.f, 0.f, 0.f, 0.f};
#pragma unroll
    for (int r = 0; r < 4; ++r) { m[r] = -1e30f; ld[r] = 0.f; }

    const int nch = tile + 1;
    const int iters = (nch + 1) >> 1;
#pragma unroll 1
    for (int i = 0; i < iters; ++i) {
      const int ci = 2 * i + g2;
      const int k0 = ci * 64;     // ci may be == nch (odd tail, group 1):
      __syncthreads();            //   k0 <= 1984, staging stays in-bounds;
                                  //   causal check below skips the compute.
      // ---- stage K chunk into this group's buffer ----
#pragma unroll
      for (int s = 0; s < 2; ++s) {
        int seg = tid2 + s * 256;
        int kr = seg >> 3, d8 = (seg & 7) * 8;
        uint4 t = *(const uint4*)(base + (size_t)(k0 + kr) * C3 + N_EMBD + h * HEAD_DIM + d8);
        *(uint4*)((char*)Ksg + kr * 128 + ((d8 * 2) ^ ((kr & 7) << 4))) = t;
      }
      // ---- stage V^T rows ----
#pragma unroll
      for (int s = 0; s < 2; ++s) {
        int seg = tid2 + s * 256;
        int dr = seg >> 3, k8 = (seg & 7) * 8;
        uint4 t = *(const uint4*)(vbase + (size_t)dr * TSEQ + k0 + k8);
        *(uint4*)((char*)Vsg + dr * 128 + ((k8 * 2) ^ ((dr & 7) << 4))) = t;
      }
      __syncthreads();
      if (k0 > qr0 + 15) continue;   // wave-uniform; also covers ci >= nch

      // ---- S = Q K^T ----
      f32x4 st[4];
      __builtin_amdgcn_s_setprio(1);
#pragma unroll
      for (int kt = 0; kt < 4; ++kt) {
        const int row = kt * 16 + c;
        short8_t kf0 = *(const short8_t*)((const char*)Ksg + row * 128 + ((g * 16) ^ ((row & 7) << 4)));
        short8_t kf1 = *(const short8_t*)((const char*)Ksg + row * 128 + ((64 + g * 16) ^ ((row & 7) << 4)));
        f32x4 a2 = (f32x4){0.f, 0.f, 0.f, 0.f};
        a2 = __builtin_amdgcn_mfma_f32_16x16x32_bf16(qf[0], kf0, a2, 0, 0, 0);
        a2 = __builtin_amdgcn_mfma_f32_16x16x32_bf16(qf[1], kf1, a2, 0, 0, 0);
        st[kt] = a2;
      }
      __builtin_amdgcn_s_setprio(0);

      // ---- online softmax, log2 domain ----
      const bool full = (k0 + 63 <= qr0);
#pragma unroll
      for (int r = 0; r < 4; ++r) {
        const int qg = qr0 + g * 4 + r;
        float mx = -1e30f;
#pragma unroll
        for (int kt = 0; kt < 4; ++kt) {
          float s = st[kt][r] * SCALE_LOG2E;
          if (!full) { int kg = k0 + kt * 16 + c; if (kg > qg) s = -1e30f; }
          st[kt][r] = s;
          mx = fmaxf(mx, s);
        }
        mx = fmaxf(mx, __shfl_xor(mx, 1));
        mx = fmaxf(mx, __shfl_xor(mx, 2));
        mx = fmaxf(mx, __shfl_xor(mx, 4));
        mx = fmaxf(mx, __shfl_xor(mx, 8));
        float mnew = fmaxf(m[r], mx);
        float corr = exp2f(m[r] - mnew);
        m[r] = mnew;
        float rs = 0.f;
        const int row = g * 4 + r;
#pragma unroll
        for (int kt = 0; kt < 4; ++kt) {
          float p = exp2f(st[kt][r] - mnew);
          rs += p;
          *(unsigned short*)((char*)Psw + row * 128 +
                             (((kt * 16 + c) * 2) ^ ((row & 7) << 4))) = f2bf(p);
        }
        rs += __shfl_xor(rs, 1);
        rs += __shfl_xor(rs, 2);
        rs += __shfl_xor(rs, 4);
        rs += __shfl_xor(rs, 8);
        ld[r] = ld[r] * corr + rs;
#pragma unroll
        for (int dt = 0; dt < 4; ++dt) o[dt][r] *= corr;
      }
      // ---- O += P V ----
      short8_t pf[2];
#pragma unroll
      for (int kc = 0; kc < 2; ++kc)
        pf[kc] = *(const short8_t*)((const char*)Psw + c * 128 +
                                    ((64 * kc + g * 16) ^ ((c & 7) << 4)));
      __builtin_amdgcn_s_setprio(1);
#pragma unroll
      for (int dt = 0; dt < 4; ++dt) {
        const int row = dt * 16 + c;
#pragma unroll
        for (int kc = 0; kc < 2; ++kc) {
          short8_t vf = *(const short8_t*)((const char*)Vsg + row * 128 +
                                           ((64 * kc + g * 16) ^ ((row & 7) << 4)));
          o[dt] = __builtin_amdgcn_mfma_f32_16x16x32_bf16(pf[kc], vf, o[dt], 0, 0, 0);
        }
      }
      __builtin_amdgcn_s_setprio(0);
    }

    // ---- cross-group combine (exact flash merge) ----
    __syncthreads();                      // all chunk work done; K1/V1 free
    if (g2 == 1) {
      float* ow = osc + wg * 1024;
      float* ml = mlsc + wg * 512;        // 512 f32 stride per wave (2KB)
#pragma unroll
      for (int r = 0; r < 4; ++r) {
        const int row = g * 4 + r;
        ml[row] = m[r];
        ml[16 + row] = ld[r];
#pragma unroll
        for (int dt = 0; dt < 4; ++dt)
          ow[row * 64 + dt * 16 + c] = o[dt][r];
      }
    }
    __syncthreads();
    if (g2 == 0) {
      float* ow = osc + wg * 1024;
      float* ml = mlsc + wg * 512;
#pragma unroll
      for (int r = 0; r < 4; ++r) {
        const int row = g * 4 + r;
        float m1 = ml[row], l1 = ml[16 + row];
        float ms = fmaxf(m[r], m1);
        float c0 = exp2f(m[r] - ms);
        float c1 = exp2f(m1 - ms);
        float inv = 1.f / (ld[r] * c0 + l1 * c1);
        const size_t rowoff = ((size_t)b * TSEQ + qr0 + row) * N_EMBD + h * HEAD_DIM;
#pragma unroll
        for (int dt = 0; dt < 4; ++dt)
          y[rowoff + dt * 16 + c] =
              f2bf((o[dt][r] * c0 + ow[row * 64 + dt * 16 + c] * c1) * inv);
      }
    }
    // next half's first __syncthreads (top of chunk loop) fences the LDS reuse
  }
}

extern "C" void kernel_launch(void* const* d_in, const int* in_sizes, int n_in,
                              void* d_out, int out_size, void* d_ws, size_t ws_size,
                              hipStream_t stream) {
  const float* x      = (const float*)d_in[0];
  const float* W_attn = (const float*)d_in[1];
  const float* b_attn = (const float*)d_in[2];
  const float* W_proj = (const float*)d_in[3];
  const float* b_proj = (const float*)d_in[4];
  float* out = (float*)d_out;

  const int M = BSZ * TSEQ;  // 4096

  unsigned short* xb   = (unsigned short*)d_ws;                 // [M,C]      8.4 MB
  unsigned short* Wta  = xb + (size_t)M * N_EMBD;               // [3C,C]     6.3 MB
  unsigned short* Wtp  = Wta + (size_t)C3 * N_EMBD;             // [C,C]      2.1 MB
  unsigned short* qkvb = Wtp + (size_t)N_EMBD * N_EMBD;         // [B,T,3C]  25.2 MB
  unsigned short* yatt = qkvb + (size_t)M * C3;                 // [B,T,C]    8.4 MB
  unsigned short* vtb  = yatt + (size_t)M * N_EMBD;             // [B*H,D,T]  8.4 MB

  conv_vec<<<2048, 256, 0, stream>>>(x, xb, M * N_EMBD / 8);
  conv_transpose<<<dim3(C3 / 32, N_EMBD / 32), 256, 0, stream>>>(W_attn, Wta, N_EMBD, C3);
  conv_transpose<<<dim3(N_EMBD / 32, N_EMBD / 32), 256, 0, stream>>>(W_proj, Wtp, N_EMBD, N_EMBD);

  gemm_mfma<unsigned short><<<dim3(C3 / 128, M / 128), 256, 0, stream>>>(
      xb, Wta, b_attn, qkvb, M, C3, N_EMBD);

  conv_vT<<<dim3(TSEQ / 32, HEAD_DIM / 32, BSZ * N_HEAD), 256, 0, stream>>>(qkvb, vtb);

  // 512-thread blocks: 2 chunk-groups x 4 waves; pair (31-p, p) -> uniform work
  attn_mfma<<<dim3(TSEQ / 128, N_HEAD, BSZ), 512, 0, stream>>>(qkvb, vtb, yatt);

  gemm_mfma<float><<<dim3(N_EMBD / 128, M / 128), 256, 0, stream>>>(
      yatt, Wtp, b_proj, out, M, N_EMBD, N_EMBD);
}